// Round 4
// baseline (233.281 us; speedup 1.0000x reference)
//
#include <hip/hip_runtime.h>

// out[b,c,l] = sum_{k=0..6} x[b,c,l+k-3] * w[b, c%G, k, l]   (zero-pad in l)
// B=8, C=256, L=8192, G=64, K=7.
// Streaming, software-pipelined: each wave owns half an output row (4096 floats),
// 16 iterations of 256 floats, prefetching iter+1 (7 w + 3 x float4 loads) while
// computing iter. Block = 4 waves = the 4 channels of one (b,g,half) -> w loads
// are identical addresses across waves (L1 broadcast). Whole grid co-resident:
// 1024 blocks x 4 waves = 16 waves/CU at <=128 VGPR.

constexpr int Bn = 8, Cn = 256, Ln = 8192, Gn = 64, Kn = 7;
constexpr int BLOCK = 256;
constexpr int CHUNK = 256;            // floats per wave-iteration (64 lanes * 4)
constexpr int ITERS = (Ln / 2) / CHUNK; // 16

__device__ __forceinline__ float4 ld4(const float* p) {
    return *reinterpret_cast<const float4*>(p);
}

struct Frag {
    float4 W0, W1, W2, W3, W4, W5, W6;  // contiguous: &W0.x is a float[28]
    float4 A, B, C;                     // x window [lg-4, lg+8)
};

__device__ __forceinline__ void load_frag(Frag& f, const float* wp,
                                          const float* xp, int lg) {
    f.W0 = ld4(wp);
    f.W1 = ld4(wp + Ln);
    f.W2 = ld4(wp + 2 * Ln);
    f.W3 = ld4(wp + 3 * Ln);
    f.W4 = ld4(wp + 4 * Ln);
    f.W5 = ld4(wp + 5 * Ln);
    f.W6 = ld4(wp + 6 * Ln);
    const float4 z = make_float4(0.f, 0.f, 0.f, 0.f);
    f.A = (lg >= 4)      ? ld4(xp - 4) : z;
    f.B =                  ld4(xp);
    f.C = (lg + 4 < Ln)  ? ld4(xp + 4) : z;
}

__device__ __forceinline__ void compute_store(const Frag& f, float* op) {
    float xs[12];
    xs[0] = f.A.x; xs[1] = f.A.y; xs[2]  = f.A.z; xs[3]  = f.A.w;
    xs[4] = f.B.x; xs[5] = f.B.y; xs[6]  = f.B.z; xs[7]  = f.B.w;
    xs[8] = f.C.x; xs[9] = f.C.y; xs[10] = f.C.z; xs[11] = f.C.w;
    const float* Wf = &f.W0.x;          // Wf[k*4+i] == W_k component i
    float4 o;
    float* opx = &o.x;
#pragma unroll
    for (int i = 0; i < 4; ++i) {
        float acc = 0.f;
#pragma unroll
        for (int k = 0; k < Kn; ++k)
            acc = fmaf(xs[1 + i + k], Wf[k * 4 + i], acc);
        opx[i] = acc;
    }
    *reinterpret_cast<float4*>(op) = o;
}

__global__ __launch_bounds__(BLOCK, 4) void ska1d_kernel(
    const float* __restrict__ x,
    const float* __restrict__ w,
    float* __restrict__ out)
{
    const int bid  = blockIdx.x;
    const int half = bid & 1;
    const int g    = (bid >> 1) & (Gn - 1);
    const int b    = bid >> 7;
    const int wv   = (int)threadIdx.x >> 6;
    const int lane = (int)threadIdx.x & 63;
    const int c    = g + wv * Gn;                 // c % Gn == g
    const int l0   = half * (Ln / 2) + lane * 4;  // this wave's first lane-base

    const float* wp = w   + ((size_t)(b * Gn + g) * Kn) * Ln + l0;
    const float* xp = x   + ((size_t)(b * Cn + c)) * Ln + l0;
    float*       op = out + ((size_t)(b * Cn + c)) * Ln + l0;

    Frag f0, f1;
    load_frag(f0, wp, xp, l0);                    // prologue: iter 0

    for (int it = 0; it < ITERS; it += 2) {
        // -- prefetch iter it+1 into f1 (clamped; redundant reload at tail is harmless)
        {
            const int nidx = (it + 1 < ITERS) ? it + 1 : it;
            const int off  = nidx * CHUNK;
            load_frag(f1, wp + off, xp + off, l0 + off);
        }
        __builtin_amdgcn_sched_barrier(0);
        compute_store(f0, op + it * CHUNK);

        // -- prefetch iter it+2 into f0
        {
            const int nidx = (it + 2 < ITERS) ? it + 2 : ITERS - 1;
            const int off  = nidx * CHUNK;
            load_frag(f0, wp + off, xp + off, l0 + off);
        }
        __builtin_amdgcn_sched_barrier(0);
        compute_store(f1, op + (it + 1) * CHUNK);
    }
}

extern "C" void kernel_launch(void* const* d_in, const int* in_sizes, int n_in,
                              void* d_out, int out_size, void* d_ws, size_t ws_size,
                              hipStream_t stream)
{
    const float* x = (const float*)d_in[0];
    const float* w = (const float*)d_in[1];
    float* out     = (float*)d_out;

    const int grid = Bn * Gn * 2;   // 1024 blocks: (b, g, half)
    ska1d_kernel<<<grid, BLOCK, 0, stream>>>(x, w, out);
}